// Round 15
// baseline (49.853 us; speedup 1.0000x reference)
//
#include <hip/hip_runtime.h>

typedef unsigned int uint;
typedef unsigned short ushort_t;
typedef __attribute__((ext_vector_type(8))) short short8v;   // 8 bf16 (4 VGPRs)
typedef __attribute__((ext_vector_type(4))) float f32x4;

#define BATCH 8
#define HH 128
#define WW 128
#define CC 64
#define NPIX (BATCH * HH * WW)   // 131072
#define KK 9
#define BN_EPS 1e-3f

__device__ __forceinline__ uint f2bfbits(float f) {
    uint u = __float_as_uint(f);
    return (u + 0x7fffu + ((u >> 16) & 1u)) >> 16;   // RNE
}

// ---- setup: w1 -> bf16 [d][c]; w2 -> bf16 transposed [k][d]; fold BN ----
__global__ void setup_kernel(const float* __restrict__ w1,
                             const float* __restrict__ b1,
                             const float* __restrict__ gamma,
                             const float* __restrict__ beta,
                             const float* __restrict__ bn_mean,
                             const float* __restrict__ bn_var,
                             const float* __restrict__ w2,
                             const float* __restrict__ b2,
                             ushort_t* __restrict__ w1b,    // [64][64] bf16: w1b[d][c] = w1[c][d]
                             ushort_t* __restrict__ w2bT,   // [16][64] bf16: w2bT[k][d] = w2[d][k]
                             float* __restrict__ scalef,    // [64]
                             float* __restrict__ biasf,     // [64]
                             float* __restrict__ b2f)       // [9]
{
    int t = blockIdx.x * blockDim.x + threadIdx.x;
    int nt = gridDim.x * blockDim.x;
    for (int idx = t; idx < CC * CC; idx += nt) {
        int d = idx >> 6, c = idx & 63;
        w1b[idx] = (ushort_t)f2bfbits(w1[c * CC + d]);
    }
    for (int idx = t; idx < 16 * CC; idx += nt) {
        int k = idx >> 6, d = idx & 63;
        w2bT[idx] = (k < KK) ? (ushort_t)f2bfbits(w2[d * KK + k]) : (ushort_t)0;
    }
    if (t < CC) {
        float s = gamma[t] * rsqrtf(bn_var[t] + BN_EPS);
        scalef[t] = s;
        biasf[t] = (b1[t] - bn_mean[t]) * s + beta[t];
    }
    if (t < KK) b2f[t] = b2[t];
}

// ---- fused, barrier-free, MAX prefetch: all tap loads in flight before use ----
__global__ __launch_bounds__(256) void invol_fused(
    const float* __restrict__ x,
    const ushort_t* __restrict__ w1b,
    const ushort_t* __restrict__ w2bT,
    const float* __restrict__ scalef,
    const float* __restrict__ biasf,
    const float* __restrict__ b2f,
    float* __restrict__ out,     // [NPIX][64]
    float* __restrict__ kout)    // [NPIX][9]
{
    __shared__ ushort_t hL[4][16][72];     // per-wave h (bf16), 9.2 KB (wave-private)
    __shared__ float    kS[64][12];        // kern per pixel, 3 KB (wave-private rows)

    const int t = threadIdx.x;
    const int w = __builtin_amdgcn_readfirstlane(t >> 6);
    const int l = t & 63;
    const int lq = l >> 4, lr = l & 15;
    int bid = blockIdx.x;
    bid = (bid & 7) * 256 + (bid >> 3);    // XCD swizzle (2048 = 8*256, bijective)
    const int p0 = bid * 64;

    // involution thread identity (t>>2 lies in wave w's own px range)
    const int pxl = t >> 2;
    const int c0i = (t & 3) * 16;
    const int p = p0 + pxl;
    const int b = p >> 14;
    const int i = (p >> 7) & 127;          // uniform per block (64 px in half a row)
    const int j = p & 127;

    // ---- issue A-frag loads FIRST ----
    const float* xr = x + (size_t)(p0 + w * 16 + lr) * CC;
    float4 a00 = *(const float4*)(xr + lq * 8);
    float4 a01 = *(const float4*)(xr + lq * 8 + 4);
    float4 a10 = *(const float4*)(xr + 32 + lq * 8);
    float4 a11 = *(const float4*)(xr + 32 + lq * 8 + 4);

    // ---- issue rows -1 AND 0 tap loads (24 f4, stay in flight through GEMMs) ----
    float4 gm[3][4], g0[3][4];
    {
        const int im1 = max(i - 1, 0);
        const float* rowm = x + ((size_t)b * HH + im1) * WW * CC;
        const float* row0 = x + ((size_t)b * HH + i) * WW * CC;
#pragma unroll
        for (int tj = 0; tj < 3; ++tj) {
            int jc = min(max(j + tj - 1, 0), WW - 1);
            const float4* npm = (const float4*)(rowm + (size_t)jc * CC + c0i);
            const float4* np0 = (const float4*)(row0 + (size_t)jc * CC + c0i);
#pragma unroll
            for (int f = 0; f < 4; ++f) { gm[tj][f] = npm[f]; g0[tj][f] = np0[f]; }
        }
    }

    // ---- cvt A -> bf16 frags; GEMM1 (r6/r12/r14-proven recipe) ----
    {
        short8v af[2];
        union { uint4 u; short8v s; } cv;
        cv.u.x = f2bfbits(a00.x) | (f2bfbits(a00.y) << 16);
        cv.u.y = f2bfbits(a00.z) | (f2bfbits(a00.w) << 16);
        cv.u.z = f2bfbits(a01.x) | (f2bfbits(a01.y) << 16);
        cv.u.w = f2bfbits(a01.z) | (f2bfbits(a01.w) << 16);
        af[0] = cv.s;
        cv.u.x = f2bfbits(a10.x) | (f2bfbits(a10.y) << 16);
        cv.u.y = f2bfbits(a10.z) | (f2bfbits(a10.w) << 16);
        cv.u.z = f2bfbits(a11.x) | (f2bfbits(a11.y) << 16);
        cv.u.w = f2bfbits(a11.z) | (f2bfbits(a11.w) << 16);
        af[1] = cv.s;

        f32x4 acc[4];
#pragma unroll
        for (int n = 0; n < 4; ++n) acc[n] = (f32x4){0.f, 0.f, 0.f, 0.f};
#pragma unroll
        for (int ks = 0; ks < 2; ++ks)
#pragma unroll
            for (int n = 0; n < 4; ++n) {
                short8v bf = *(const short8v*)(w1b + (n * 16 + lr) * CC + ks * 32 + lq * 8);
                acc[n] = __builtin_amdgcn_mfma_f32_16x16x32_bf16(af[ks], bf, acc[n], 0, 0, 0);
            }
        // epilogue: BN+ReLU -> bf16 -> hL (C layout: row=px=lq*4+r, col=d=n*16+lr)
#pragma unroll
        for (int n = 0; n < 4; ++n) {
            const int d = n * 16 + lr;
            const float s = scalef[d], bb = biasf[d];
#pragma unroll
            for (int r = 0; r < 4; ++r) {
                float hv = fmaxf(fmaf(acc[n][r], s, bb), 0.f);
                hL[w][lq * 4 + r][d] = (ushort_t)f2bfbits(hv);
            }
        }
    }

    // ---- issue row +1 tap loads NOW (before GEMM2's lgkm waits) ----
    float4 g1[3][4];
    {
        const int ip1 = min(i + 1, HH - 1);
        const float* rowp = x + ((size_t)b * HH + ip1) * WW * CC;
#pragma unroll
        for (int tj = 0; tj < 3; ++tj) {
            int jc = min(max(j + tj - 1, 0), WW - 1);
            const float4* np = (const float4*)(rowp + (size_t)jc * CC + c0i);
#pragma unroll
            for (int f = 0; f < 4; ++f) g1[tj][f] = np[f];
        }
    }

    // ---- GEMM2: kern = h @ w2 + b2 via MFMA (M=16, N=16 pad, K=64; r9 recipe) ----
    {
        f32x4 acc2 = (f32x4){0.f, 0.f, 0.f, 0.f};
#pragma unroll
        for (int ks = 0; ks < 2; ++ks) {
            short8v a2  = *(const short8v*)(&hL[w][lr][ks * 32 + lq * 8]);
            short8v b2v = *(const short8v*)(w2bT + lr * CC + ks * 32 + lq * 8);
            acc2 = __builtin_amdgcn_mfma_f32_16x16x32_bf16(a2, b2v, acc2, 0, 0, 0);
        }
        if (lr < KK) {
            const float bk = b2f[lr];
#pragma unroll
            for (int r = 0; r < 4; ++r)
                kS[w * 16 + lq * 4 + r][lr] = acc2[r] + bk;
        }
    }
    // same-wave handoff; dense kout drain: 36 float4 per wave
    {
        float* kbase = kout + (size_t)(p0 + w * 16) * KK;
        if (l < 36) {
            float v[4];
#pragma unroll
            for (int e = 0; e < 4; ++e) {
                int f = l * 4 + e;
                v[e] = kS[w * 16 + f / KK][f % KK];
            }
            *(f32x4*)(kbase + l * 4) = (f32x4){v[0], v[1], v[2], v[3]};
        }
    }

    // ---- involution: consume prefetched rows in age order ----
    float kern[KK];
#pragma unroll
    for (int k = 0; k < KK; ++k) kern[k] = kS[pxl][k];

    float4 accv[4];
#pragma unroll
    for (int f = 0; f < 4; ++f) accv[f] = make_float4(0.f, 0.f, 0.f, 0.f);

    // consume row -1
#pragma unroll
    for (int tj = 0; tj < 3; ++tj) {
        int jj = j + tj - 1;
        bool valid = (i > 0) && (jj >= 0) && (jj < WW);
        float kv = valid ? kern[tj] : 0.f;
#pragma unroll
        for (int f = 0; f < 4; ++f) {
            accv[f].x = fmaf(kv, gm[tj][f].x, accv[f].x);
            accv[f].y = fmaf(kv, gm[tj][f].y, accv[f].y);
            accv[f].z = fmaf(kv, gm[tj][f].z, accv[f].z);
            accv[f].w = fmaf(kv, gm[tj][f].w, accv[f].w);
        }
    }
    // consume row 0
#pragma unroll
    for (int tj = 0; tj < 3; ++tj) {
        int jj = j + tj - 1;
        bool valid = (jj >= 0) && (jj < WW);
        float kv = valid ? kern[3 + tj] : 0.f;
#pragma unroll
        for (int f = 0; f < 4; ++f) {
            accv[f].x = fmaf(kv, g0[tj][f].x, accv[f].x);
            accv[f].y = fmaf(kv, g0[tj][f].y, accv[f].y);
            accv[f].z = fmaf(kv, g0[tj][f].z, accv[f].z);
            accv[f].w = fmaf(kv, g0[tj][f].w, accv[f].w);
        }
    }
    // consume row +1
#pragma unroll
    for (int tj = 0; tj < 3; ++tj) {
        int jj = j + tj - 1;
        bool valid = (i < HH - 1) && (jj >= 0) && (jj < WW);
        float kv = valid ? kern[6 + tj] : 0.f;
#pragma unroll
        for (int f = 0; f < 4; ++f) {
            accv[f].x = fmaf(kv, g1[tj][f].x, accv[f].x);
            accv[f].y = fmaf(kv, g1[tj][f].y, accv[f].y);
            accv[f].z = fmaf(kv, g1[tj][f].z, accv[f].z);
            accv[f].w = fmaf(kv, g1[tj][f].w, accv[f].w);
        }
    }

    float4* op = (float4*)(out + (size_t)p * CC + c0i);
#pragma unroll
    for (int f = 0; f < 4; ++f) op[f] = accv[f];
}

extern "C" void kernel_launch(void* const* d_in, const int* in_sizes, int n_in,
                              void* d_out, int out_size, void* d_ws, size_t ws_size,
                              hipStream_t stream) {
    const float* x       = (const float*)d_in[0];
    const float* w1      = (const float*)d_in[1];
    const float* b1      = (const float*)d_in[2];
    const float* gamma   = (const float*)d_in[3];
    const float* beta    = (const float*)d_in[4];
    const float* bn_mean = (const float*)d_in[5];
    const float* bn_var  = (const float*)d_in[6];
    const float* w2      = (const float*)d_in[7];
    const float* b2      = (const float*)d_in[8];

    ushort_t* w1b  = (ushort_t*)d_ws;                // 4096 ush = 8192 B
    ushort_t* w2bT = w1b + CC * CC;                  // 1024 ush = 2048 B
    float* scalef  = (float*)(w2bT + 16 * CC);       // 64
    float* biasf   = scalef + CC;                    // 64
    float* b2f     = biasf + CC;                     // 9

    float* out  = (float*)d_out;
    float* kout = out + (size_t)NPIX * CC;

    hipLaunchKernelGGL(setup_kernel, dim3(20), dim3(256), 0, stream,
                       w1, b1, gamma, beta, bn_mean, bn_var, w2, b2,
                       w1b, w2bT, scalef, biasf, b2f);

    hipLaunchKernelGGL(invol_fused, dim3(NPIX / 64), dim3(256), 0, stream,
                       x, w1b, w2bT, scalef, biasf, b2f, out, kout);
}

// Round 16
// 38.109 us; speedup vs baseline: 1.3082x; 1.3082x over previous
//
#include <hip/hip_runtime.h>

typedef unsigned int uint;
typedef unsigned short ushort_t;
typedef __attribute__((ext_vector_type(8))) short short8v;   // 8 bf16 (4 VGPRs)
typedef __attribute__((ext_vector_type(4))) float f32x4;

#define BATCH 8
#define HH 128
#define WW 128
#define CC 64
#define NPIX (BATCH * HH * WW)   // 131072
#define KK 9
#define BN_EPS 1e-3f

__device__ __forceinline__ uint f2bfbits(float f) {
    uint u = __float_as_uint(f);
    return (u + 0x7fffu + ((u >> 16) & 1u)) >> 16;   // RNE
}
__device__ __forceinline__ float bflo(uint u) { return __uint_as_float(u << 16); }
__device__ __forceinline__ float bfhi(uint u) { return __uint_as_float(u & 0xffff0000u); }

// ---- setup: w1 -> bf16 [d][c]; w2 -> bf16 transposed [k][d]; fold BN ----
__global__ void setup_kernel(const float* __restrict__ w1,
                             const float* __restrict__ b1,
                             const float* __restrict__ gamma,
                             const float* __restrict__ beta,
                             const float* __restrict__ bn_mean,
                             const float* __restrict__ bn_var,
                             const float* __restrict__ w2,
                             const float* __restrict__ b2,
                             ushort_t* __restrict__ w1b,    // [64][64] bf16: w1b[d][c] = w1[c][d]
                             ushort_t* __restrict__ w2bT,   // [16][64] bf16: w2bT[k][d] = w2[d][k]
                             float* __restrict__ scalef,    // [64]
                             float* __restrict__ biasf,     // [64]
                             float* __restrict__ b2f)       // [9]
{
    int t = blockIdx.x * blockDim.x + threadIdx.x;
    int nt = gridDim.x * blockDim.x;
    for (int idx = t; idx < CC * CC; idx += nt) {
        int d = idx >> 6, c = idx & 63;
        w1b[idx] = (ushort_t)f2bfbits(w1[c * CC + d]);
    }
    for (int idx = t; idx < 16 * CC; idx += nt) {
        int k = idx >> 6, d = idx & 63;
        w2bT[idx] = (k < KK) ? (ushort_t)f2bfbits(w2[d * KK + k]) : (ushort_t)0;
    }
    if (t < CC) {
        float s = gamma[t] * rsqrtf(bn_var[t] + BN_EPS);
        scalef[t] = s;
        biasf[t] = (b1[t] - bn_mean[t]) * s + beta[t];
    }
    if (t < KK) b2f[t] = b2[t];
}

// ---- fused: coalesced 3-row stage -> one barrier -> GEMMs + LDS involution ----
__global__ __launch_bounds__(256) void invol_fused(
    const float* __restrict__ x,
    const ushort_t* __restrict__ w1b,
    const ushort_t* __restrict__ w2bT,
    const float* __restrict__ scalef,
    const float* __restrict__ biasf,
    const float* __restrict__ b2f,
    float* __restrict__ out,     // [NPIX][64]
    float* __restrict__ kout)    // [NPIX][9]
{
    __shared__ ushort_t xrow[3][66][72];   // 3-row tap window (bf16), 28.5 KB
    __shared__ ushort_t hL[4][16][72];     // per-wave h (bf16), 9.2 KB (wave-private)
    __shared__ float    kS[64][12];        // kern per pixel, 3 KB (wave-private rows)

    const int t = threadIdx.x;
    const int w = __builtin_amdgcn_readfirstlane(t >> 6);
    const int l = t & 63;
    const int lq = l >> 4, lr = l & 15;
    int bid = blockIdx.x;
    bid = (bid & 7) * 256 + (bid >> 3);    // XCD swizzle (2048 = 8*256, bijective)
    const int p0 = bid * 64;

    const int b  = p0 >> 14;
    const int i  = (p0 >> 7) & 127;        // block-uniform row
    const int j0 = p0 & 127;               // 0 or 64

    // ---- phase 0: COALESCED stage of rows i-1,i,i+1 × px [j0-1, j0+64] -> bf16 LDS ----
    // each instruction: 64 lanes x 16B = 1KB contiguous (16 cache lines, fill-pattern)
#pragma unroll
    for (int r = 0; r < 3; ++r) {
        const int ir = min(max(i + r - 1, 0), HH - 1);
        const float* rowp = x + ((size_t)b * HH + ir) * WW * CC;
#pragma unroll
        for (int s = 0; s < 4; ++s) {
            int u = t + s * 256;                 // u < 1024 < 1056 always valid
            int slot = u >> 4, c4 = u & 15;
            int jj = min(max(j0 + slot - 1, 0), WW - 1);   // clamp; OOB weight zeroed later
            float4 v = *(const float4*)(rowp + (size_t)jj * CC + c4 * 4);
            uint2 pk;
            pk.x = f2bfbits(v.x) | (f2bfbits(v.y) << 16);
            pk.y = f2bfbits(v.z) | (f2bfbits(v.w) << 16);
            *(uint2*)(&xrow[r][slot][c4 * 4]) = pk;
        }
        if (t < 32) {                            // tail: u = 1024..1055
            int u = t + 1024;
            int slot = u >> 4, c4 = u & 15;
            int jj = min(max(j0 + slot - 1, 0), WW - 1);
            float4 v = *(const float4*)(rowp + (size_t)jj * CC + c4 * 4);
            uint2 pk;
            pk.x = f2bfbits(v.x) | (f2bfbits(v.y) << 16);
            pk.y = f2bfbits(v.z) | (f2bfbits(v.w) << 16);
            *(uint2*)(&xrow[r][slot][c4 * 4]) = pk;
        }
    }
    __syncthreads();   // the ONLY barrier

    // ---- GEMM1: wave w owns px [w*16,w*16+16); A from center LDS row (r6 recipe) ----
    {
        short8v af[2];
#pragma unroll
        for (int ks = 0; ks < 2; ++ks)
            af[ks] = *(const short8v*)(&xrow[1][w * 16 + lr + 1][ks * 32 + lq * 8]);

        f32x4 acc[4];
#pragma unroll
        for (int n = 0; n < 4; ++n) acc[n] = (f32x4){0.f, 0.f, 0.f, 0.f};
#pragma unroll
        for (int ks = 0; ks < 2; ++ks)
#pragma unroll
            for (int n = 0; n < 4; ++n) {
                short8v bf = *(const short8v*)(w1b + (n * 16 + lr) * CC + ks * 32 + lq * 8);
                acc[n] = __builtin_amdgcn_mfma_f32_16x16x32_bf16(af[ks], bf, acc[n], 0, 0, 0);
            }
        // epilogue: BN+ReLU -> bf16 -> hL (C layout: row=px=lq*4+r, col=d=n*16+lr)
#pragma unroll
        for (int n = 0; n < 4; ++n) {
            const int d = n * 16 + lr;
            const float s = scalef[d], bb = biasf[d];
#pragma unroll
            for (int r = 0; r < 4; ++r) {
                float hv = fmaxf(fmaf(acc[n][r], s, bb), 0.f);
                hL[w][lq * 4 + r][d] = (ushort_t)f2bfbits(hv);
            }
        }
    }
    // same-wave LDS handoff (compiler lgkmcnt; r9/r12/r14-proven)

    // ---- GEMM2: kern = h @ w2 + b2 via MFMA (M=16, N=16 pad, K=64; r9 recipe) ----
    {
        f32x4 acc2 = (f32x4){0.f, 0.f, 0.f, 0.f};
#pragma unroll
        for (int ks = 0; ks < 2; ++ks) {
            short8v a2  = *(const short8v*)(&hL[w][lr][ks * 32 + lq * 8]);
            short8v b2v = *(const short8v*)(w2bT + lr * CC + ks * 32 + lq * 8);
            acc2 = __builtin_amdgcn_mfma_f32_16x16x32_bf16(a2, b2v, acc2, 0, 0, 0);
        }
        if (lr < KK) {
            const float bk = b2f[lr];
#pragma unroll
            for (int r = 0; r < 4; ++r)
                kS[w * 16 + lq * 4 + r][lr] = acc2[r] + bk;
        }
    }
    // same-wave handoff; dense kout drain: 36 contiguous float4 per wave
    {
        float* kbase = kout + (size_t)(p0 + w * 16) * KK;
        if (l < 36) {
            float v[4];
#pragma unroll
            for (int e = 0; e < 4; ++e) {
                int f = l * 4 + e;
                v[e] = kS[w * 16 + f / KK][f % KK];
            }
            *(f32x4*)(kbase + l * 4) = (f32x4){v[0], v[1], v[2], v[3]};
        }
    }

    // ---- involution from LDS: thread = (pxl = t>>2, 16-ch quarter) ----
    {
        const int pxl = t >> 2;
        const int c0i = (t & 3) * 16;

        float kern[KK];
#pragma unroll
        for (int k = 0; k < KK; ++k) kern[k] = kS[pxl][k];

        float4 accv[4];
#pragma unroll
        for (int f = 0; f < 4; ++f) accv[f] = make_float4(0.f, 0.f, 0.f, 0.f);

#pragma unroll
        for (int ti = 0; ti < 3; ++ti) {
            const int ii = i + ti - 1;
            if (ii < 0 || ii >= HH) continue;          // block-uniform skip
#pragma unroll
            for (int tj = 0; tj < 3; ++tj) {
                int jj = j0 + pxl + tj - 1;
                bool valid = (jj >= 0) && (jj < WW);
                float kv = valid ? kern[ti * 3 + tj] : 0.f;
                const uint4 u0 = *(const uint4*)(&xrow[ti][pxl + tj][c0i]);
                const uint4 u1 = *(const uint4*)(&xrow[ti][pxl + tj][c0i + 8]);
                accv[0].x = fmaf(kv, bflo(u0.x), accv[0].x);
                accv[0].y = fmaf(kv, bfhi(u0.x), accv[0].y);
                accv[0].z = fmaf(kv, bflo(u0.y), accv[0].z);
                accv[0].w = fmaf(kv, bfhi(u0.y), accv[0].w);
                accv[1].x = fmaf(kv, bflo(u0.z), accv[1].x);
                accv[1].y = fmaf(kv, bfhi(u0.z), accv[1].y);
                accv[1].z = fmaf(kv, bflo(u0.w), accv[1].z);
                accv[1].w = fmaf(kv, bfhi(u0.w), accv[1].w);
                accv[2].x = fmaf(kv, bflo(u1.x), accv[2].x);
                accv[2].y = fmaf(kv, bfhi(u1.x), accv[2].y);
                accv[2].z = fmaf(kv, bflo(u1.y), accv[2].z);
                accv[2].w = fmaf(kv, bfhi(u1.y), accv[2].w);
                accv[3].x = fmaf(kv, bflo(u1.z), accv[3].x);
                accv[3].y = fmaf(kv, bfhi(u1.z), accv[3].y);
                accv[3].z = fmaf(kv, bflo(u1.w), accv[3].z);
                accv[3].w = fmaf(kv, bfhi(u1.w), accv[3].w);
            }
        }

        float4* op = (float4*)(out + (size_t)(p0 + pxl) * CC + c0i);
#pragma unroll
        for (int f = 0; f < 4; ++f) op[f] = accv[f];
    }
}

extern "C" void kernel_launch(void* const* d_in, const int* in_sizes, int n_in,
                              void* d_out, int out_size, void* d_ws, size_t ws_size,
                              hipStream_t stream) {
    const float* x       = (const float*)d_in[0];
    const float* w1      = (const float*)d_in[1];
    const float* b1      = (const float*)d_in[2];
    const float* gamma   = (const float*)d_in[3];
    const float* beta    = (const float*)d_in[4];
    const float* bn_mean = (const float*)d_in[5];
    const float* bn_var  = (const float*)d_in[6];
    const float* w2      = (const float*)d_in[7];
    const float* b2      = (const float*)d_in[8];

    ushort_t* w1b  = (ushort_t*)d_ws;                // 4096 ush = 8192 B
    ushort_t* w2bT = w1b + CC * CC;                  // 1024 ush = 2048 B
    float* scalef  = (float*)(w2bT + 16 * CC);       // 64
    float* biasf   = scalef + CC;                    // 64
    float* b2f     = biasf + CC;                     // 9

    float* out  = (float*)d_out;
    float* kout = out + (size_t)NPIX * CC;

    hipLaunchKernelGGL(setup_kernel, dim3(20), dim3(256), 0, stream,
                       w1, b1, gamma, beta, bn_mean, bn_var, w2, b2,
                       w1b, w2bT, scalef, biasf, b2f);

    hipLaunchKernelGGL(invol_fused, dim3(NPIX / 64), dim3(256), 0, stream,
                       x, w1b, w2bT, scalef, biasf, b2f, out, kout);
}

// Round 17
// 34.603 us; speedup vs baseline: 1.4407x; 1.1013x over previous
//
#include <hip/hip_runtime.h>

typedef unsigned int uint;
typedef unsigned short ushort_t;
typedef __attribute__((ext_vector_type(8))) short short8v;   // 8 bf16 (4 VGPRs)
typedef __attribute__((ext_vector_type(4))) float f32x4;

#define BATCH 8
#define HH 128
#define WW 128
#define CC 64
#define NPIX (BATCH * HH * WW)   // 131072
#define KK 9
#define BN_EPS 1e-3f

__device__ __forceinline__ uint f2bfbits(float f) {
    uint u = __float_as_uint(f);
    return (u + 0x7fffu + ((u >> 16) & 1u)) >> 16;   // RNE
}
__device__ __forceinline__ float bflo(uint u) { return __uint_as_float(u << 16); }
__device__ __forceinline__ float bfhi(uint u) { return __uint_as_float(u & 0xffff0000u); }

// ---- setup: w1 -> bf16 [d][c]; w2 -> bf16 transposed [k][d]; fold BN ----
__global__ void setup_kernel(const float* __restrict__ w1,
                             const float* __restrict__ b1,
                             const float* __restrict__ gamma,
                             const float* __restrict__ beta,
                             const float* __restrict__ bn_mean,
                             const float* __restrict__ bn_var,
                             const float* __restrict__ w2,
                             const float* __restrict__ b2,
                             ushort_t* __restrict__ w1b,    // [64][64] bf16: w1b[d][c] = w1[c][d]
                             ushort_t* __restrict__ w2bT,   // [16][64] bf16: w2bT[k][d] = w2[d][k]
                             float* __restrict__ scalef,    // [64]
                             float* __restrict__ biasf,     // [64]
                             float* __restrict__ b2f)       // [9]
{
    int t = blockIdx.x * blockDim.x + threadIdx.x;
    int nt = gridDim.x * blockDim.x;
    for (int idx = t; idx < CC * CC; idx += nt) {
        int d = idx >> 6, c = idx & 63;
        w1b[idx] = (ushort_t)f2bfbits(w1[c * CC + d]);
    }
    for (int idx = t; idx < 16 * CC; idx += nt) {
        int k = idx >> 6, d = idx & 63;
        w2bT[idx] = (k < KK) ? (ushort_t)f2bfbits(w2[d * KK + k]) : (ushort_t)0;
    }
    if (t < CC) {
        float s = gamma[t] * rsqrtf(bn_var[t] + BN_EPS);
        scalef[t] = s;
        biasf[t] = (b1[t] - bn_mean[t]) * s + beta[t];
    }
    if (t < KK) b2f[t] = b2[t];
}

// ---- fused: coalesced stage -> GEMMs + LDS involution -> LDS-transposed dense store ----
__global__ __launch_bounds__(256) void invol_fused(
    const float* __restrict__ x,
    const ushort_t* __restrict__ w1b,
    const ushort_t* __restrict__ w2bT,
    const float* __restrict__ scalef,
    const float* __restrict__ biasf,
    const float* __restrict__ b2f,
    float* __restrict__ out,     // [NPIX][64]
    float* __restrict__ kout)    // [NPIX][9]
{
    __shared__ __align__(16) unsigned char smem[40832];
    ushort_t (*xrow)[66][72] = (ushort_t (*)[66][72])smem;            // [3][66][72] bf16, 28512 B
    ushort_t (*hL)[16][72]   = (ushort_t (*)[16][72])(smem + 28512);  // [4][16][72] bf16, 9216 B
    float    (*kS)[12]       = (float (*)[12])(smem + 37728);         // [64][12] f32, 3072 B
    float    (*fst)[68]      = (float (*)[68])smem;                   // [64][68] f32 reuse (17408 B)

    const int t = threadIdx.x;
    const int w = __builtin_amdgcn_readfirstlane(t >> 6);
    const int l = t & 63;
    const int lq = l >> 4, lr = l & 15;
    int bid = blockIdx.x;
    bid = (bid & 7) * 256 + (bid >> 3);    // XCD swizzle (2048 = 8*256, bijective)
    const int p0 = bid * 64;

    const int b  = p0 >> 14;
    const int i  = (p0 >> 7) & 127;        // block-uniform row
    const int j0 = p0 & 127;               // 0 or 64

    // ---- phase 0: COALESCED stage rows i-1,i,i+1 × px [j0-1, j0+64] -> bf16 LDS ----
#pragma unroll
    for (int r = 0; r < 3; ++r) {
        const int ir = min(max(i + r - 1, 0), HH - 1);
        const float* rowp = x + ((size_t)b * HH + ir) * WW * CC;
#pragma unroll
        for (int s = 0; s < 4; ++s) {
            int u = t + s * 256;
            int slot = u >> 4, c4 = u & 15;
            int jj = min(max(j0 + slot - 1, 0), WW - 1);
            float4 v = *(const float4*)(rowp + (size_t)jj * CC + c4 * 4);
            uint2 pk;
            pk.x = f2bfbits(v.x) | (f2bfbits(v.y) << 16);
            pk.y = f2bfbits(v.z) | (f2bfbits(v.w) << 16);
            *(uint2*)(&xrow[r][slot][c4 * 4]) = pk;
        }
        if (t < 32) {
            int u = t + 1024;
            int slot = u >> 4, c4 = u & 15;
            int jj = min(max(j0 + slot - 1, 0), WW - 1);
            float4 v = *(const float4*)(rowp + (size_t)jj * CC + c4 * 4);
            uint2 pk;
            pk.x = f2bfbits(v.x) | (f2bfbits(v.y) << 16);
            pk.y = f2bfbits(v.z) | (f2bfbits(v.w) << 16);
            *(uint2*)(&xrow[r][slot][c4 * 4]) = pk;
        }
    }
    __syncthreads();   // barrier 1

    // ---- GEMM1: wave w owns px [w*16,w*16+16); A from center LDS row (r6 recipe) ----
    {
        short8v af[2];
#pragma unroll
        for (int ks = 0; ks < 2; ++ks)
            af[ks] = *(const short8v*)(&xrow[1][w * 16 + lr + 1][ks * 32 + lq * 8]);

        f32x4 acc[4];
#pragma unroll
        for (int n = 0; n < 4; ++n) acc[n] = (f32x4){0.f, 0.f, 0.f, 0.f};
#pragma unroll
        for (int ks = 0; ks < 2; ++ks)
#pragma unroll
            for (int n = 0; n < 4; ++n) {
                short8v bf = *(const short8v*)(w1b + (n * 16 + lr) * CC + ks * 32 + lq * 8);
                acc[n] = __builtin_amdgcn_mfma_f32_16x16x32_bf16(af[ks], bf, acc[n], 0, 0, 0);
            }
#pragma unroll
        for (int n = 0; n < 4; ++n) {
            const int d = n * 16 + lr;
            const float s = scalef[d], bb = biasf[d];
#pragma unroll
            for (int r = 0; r < 4; ++r) {
                float hv = fmaxf(fmaf(acc[n][r], s, bb), 0.f);
                hL[w][lq * 4 + r][d] = (ushort_t)f2bfbits(hv);
            }
        }
    }
    // same-wave LDS handoff (compiler lgkmcnt)

    // ---- GEMM2: kern = h @ w2 + b2 via MFMA (M=16, N=16 pad, K=64; r9 recipe) ----
    {
        f32x4 acc2 = (f32x4){0.f, 0.f, 0.f, 0.f};
#pragma unroll
        for (int ks = 0; ks < 2; ++ks) {
            short8v a2  = *(const short8v*)(&hL[w][lr][ks * 32 + lq * 8]);
            short8v b2v = *(const short8v*)(w2bT + lr * CC + ks * 32 + lq * 8);
            acc2 = __builtin_amdgcn_mfma_f32_16x16x32_bf16(a2, b2v, acc2, 0, 0, 0);
        }
        if (lr < KK) {
            const float bk = b2f[lr];
#pragma unroll
            for (int r = 0; r < 4; ++r)
                kS[w * 16 + lq * 4 + r][lr] = acc2[r] + bk;
        }
    }
    // same-wave handoff; dense kout drain: 36 contiguous float4 per wave
    {
        float* kbase = kout + (size_t)(p0 + w * 16) * KK;
        if (l < 36) {
            float v[4];
#pragma unroll
            for (int e = 0; e < 4; ++e) {
                int f = l * 4 + e;
                v[e] = kS[w * 16 + f / KK][f % KK];
            }
            *(f32x4*)(kbase + l * 4) = (f32x4){v[0], v[1], v[2], v[3]};
        }
    }

    // ---- involution from LDS: thread = (pxl = t>>2, 16-ch quarter) ----
    const int pxl = t >> 2;
    const int c0i = (t & 3) * 16;

    float4 accv[4];
#pragma unroll
    for (int f = 0; f < 4; ++f) accv[f] = make_float4(0.f, 0.f, 0.f, 0.f);
    {
        float kern[KK];
#pragma unroll
        for (int k = 0; k < KK; ++k) kern[k] = kS[pxl][k];

#pragma unroll
        for (int ti = 0; ti < 3; ++ti) {
            const int ii = i + ti - 1;
            if (ii < 0 || ii >= HH) continue;          // block-uniform skip
#pragma unroll
            for (int tj = 0; tj < 3; ++tj) {
                int jj = j0 + pxl + tj - 1;
                bool valid = (jj >= 0) && (jj < WW);
                float kv = valid ? kern[ti * 3 + tj] : 0.f;
                const uint4 u0 = *(const uint4*)(&xrow[ti][pxl + tj][c0i]);
                const uint4 u1 = *(const uint4*)(&xrow[ti][pxl + tj][c0i + 8]);
                accv[0].x = fmaf(kv, bflo(u0.x), accv[0].x);
                accv[0].y = fmaf(kv, bfhi(u0.x), accv[0].y);
                accv[0].z = fmaf(kv, bflo(u0.y), accv[0].z);
                accv[0].w = fmaf(kv, bfhi(u0.y), accv[0].w);
                accv[1].x = fmaf(kv, bflo(u0.z), accv[1].x);
                accv[1].y = fmaf(kv, bfhi(u0.z), accv[1].y);
                accv[1].z = fmaf(kv, bflo(u0.w), accv[1].z);
                accv[1].w = fmaf(kv, bfhi(u0.w), accv[1].w);
                accv[2].x = fmaf(kv, bflo(u1.x), accv[2].x);
                accv[2].y = fmaf(kv, bfhi(u1.x), accv[2].y);
                accv[2].z = fmaf(kv, bflo(u1.y), accv[2].z);
                accv[2].w = fmaf(kv, bfhi(u1.y), accv[2].w);
                accv[3].x = fmaf(kv, bflo(u1.z), accv[3].x);
                accv[3].y = fmaf(kv, bfhi(u1.z), accv[3].y);
                accv[3].z = fmaf(kv, bflo(u1.w), accv[3].z);
                accv[3].w = fmaf(kv, bfhi(u1.w), accv[3].w);
            }
        }
    }
    __syncthreads();   // barrier 2: all xrow tap reads complete -> safe to reuse

    // ---- scatter accv -> fst (padded [64][68] f32, ~4-8 way banks, one-time) ----
#pragma unroll
    for (int f = 0; f < 4; ++f)
        *(f32x4*)(&fst[pxl][(t & 3) * 16 + f * 4]) =
            (f32x4){accv[f].x, accv[f].y, accv[f].z, accv[f].w};
    __syncthreads();   // barrier 3: scatter complete

    // ---- DENSE drain: each store instr = 64 lanes x 16B contiguous (16 lines) ----
    {
        float* obase = out + (size_t)p0 * CC;
#pragma unroll
        for (int r = 0; r < 4; ++r) {
            int idx = r * 256 + t;
            int pix = idx >> 4, gr = idx & 15;
            f32x4 v = *(const f32x4*)(&fst[pix][gr * 4]);
            *(f32x4*)(obase + (size_t)idx * 4) = v;
        }
    }
}

extern "C" void kernel_launch(void* const* d_in, const int* in_sizes, int n_in,
                              void* d_out, int out_size, void* d_ws, size_t ws_size,
                              hipStream_t stream) {
    const float* x       = (const float*)d_in[0];
    const float* w1      = (const float*)d_in[1];
    const float* b1      = (const float*)d_in[2];
    const float* gamma   = (const float*)d_in[3];
    const float* beta    = (const float*)d_in[4];
    const float* bn_mean = (const float*)d_in[5];
    const float* bn_var  = (const float*)d_in[6];
    const float* w2      = (const float*)d_in[7];
    const float* b2      = (const float*)d_in[8];

    ushort_t* w1b  = (ushort_t*)d_ws;                // 4096 ush = 8192 B
    ushort_t* w2bT = w1b + CC * CC;                  // 1024 ush = 2048 B
    float* scalef  = (float*)(w2bT + 16 * CC);       // 64
    float* biasf   = scalef + CC;                    // 64
    float* b2f     = biasf + CC;                     // 9

    float* out  = (float*)d_out;
    float* kout = out + (size_t)NPIX * CC;

    hipLaunchKernelGGL(setup_kernel, dim3(20), dim3(256), 0, stream,
                       w1, b1, gamma, beta, bn_mean, bn_var, w2, b2,
                       w1b, w2bT, scalef, biasf, b2f);

    hipLaunchKernelGGL(invol_fused, dim3(NPIX / 64), dim3(256), 0, stream,
                       x, w1b, w2bT, scalef, biasf, b2f, out, kout);
}

// Round 19
// 31.929 us; speedup vs baseline: 1.5614x; 1.0837x over previous
//
#include <hip/hip_runtime.h>

typedef unsigned int uint;
typedef unsigned short ushort_t;
typedef __attribute__((ext_vector_type(8))) short short8v;   // 8 bf16 (4 VGPRs)
typedef __attribute__((ext_vector_type(4))) float f32x4;

#define BATCH 8
#define HH 128
#define WW 128
#define CC 64
#define NPIX (BATCH * HH * WW)   // 131072
#define KK 9
#define BN_EPS 1e-3f

__device__ __forceinline__ uint f2bfbits(float f) {
    uint u = __float_as_uint(f);
    return (u + 0x7fffu + ((u >> 16) & 1u)) >> 16;   // RNE
}
__device__ __forceinline__ float bflo(uint u) { return __uint_as_float(u << 16); }
__device__ __forceinline__ float bfhi(uint u) { return __uint_as_float(u & 0xffff0000u); }

// ---- setup: w1 -> bf16 [d][c]; w2 -> bf16 transposed [k][d]; fold BN ----
__global__ void setup_kernel(const float* __restrict__ w1,
                             const float* __restrict__ b1,
                             const float* __restrict__ gamma,
                             const float* __restrict__ beta,
                             const float* __restrict__ bn_mean,
                             const float* __restrict__ bn_var,
                             const float* __restrict__ w2,
                             const float* __restrict__ b2,
                             ushort_t* __restrict__ w1b,    // [64][64] bf16: w1b[d][c] = w1[c][d]
                             ushort_t* __restrict__ w2bT,   // [16][64] bf16: w2bT[k][d] = w2[d][k]
                             float* __restrict__ scalef,    // [64]
                             float* __restrict__ biasf,     // [64]
                             float* __restrict__ b2f)       // [9]
{
    int t = blockIdx.x * blockDim.x + threadIdx.x;
    int nt = gridDim.x * blockDim.x;
    for (int idx = t; idx < CC * CC; idx += nt) {
        int d = idx >> 6, c = idx & 63;
        w1b[idx] = (ushort_t)f2bfbits(w1[c * CC + d]);
    }
    for (int idx = t; idx < 16 * CC; idx += nt) {
        int k = idx >> 6, d = idx & 63;
        w2bT[idx] = (k < KK) ? (ushort_t)f2bfbits(w2[d * KK + k]) : (ushort_t)0;
    }
    if (t < CC) {
        float s = gamma[t] * rsqrtf(bn_var[t] + BN_EPS);
        scalef[t] = s;
        biasf[t] = (b1[t] - bn_mean[t]) * s + beta[t];
    }
    if (t < KK) b2f[t] = b2[t];
}

// ---- fused: dense stage (x rows + weights) -> ONE barrier -> GEMMs + dense invol ----
__global__ __launch_bounds__(256) void invol_fused(
    const float* __restrict__ x,
    const ushort_t* __restrict__ w1b,
    const ushort_t* __restrict__ w2bT,
    const float* __restrict__ scalef,
    const float* __restrict__ biasf,
    const float* __restrict__ b2f,
    float* __restrict__ out,     // [NPIX][64]
    float* __restrict__ kout)    // [NPIX][9]
{
    __shared__ ushort_t xrow[3][66][72];   // 3-row tap window (bf16), 28512 B
    __shared__ ushort_t w1L[64][72];       // w1 tile (bf16, padded), 9216 B
    __shared__ ushort_t w2L[16][72];       // w2^T tile (bf16, padded), 2304 B
    __shared__ ushort_t hL[4][16][72];     // per-wave h (bf16), 9216 B (wave-private)
    __shared__ float    kS[64][12];        // kern per pixel, 3072 B (wave-private rows)

    const int t = threadIdx.x;
    const int w = __builtin_amdgcn_readfirstlane(t >> 6);
    const int l = t & 63;
    const int lq = l >> 4, lr = l & 15;
    int bid = blockIdx.x;
    bid = (bid & 7) * 256 + (bid >> 3);    // XCD swizzle (2048 = 8*256, bijective)
    const int p0 = bid * 64;

    const int b  = p0 >> 14;
    const int i  = (p0 >> 7) & 127;        // block-uniform row
    const int j0 = p0 & 127;               // 0 or 64

    // ---- phase 0a: DENSE stage x rows i-1,i,i+1 -> bf16 LDS (1KB/instr) ----
#pragma unroll
    for (int r = 0; r < 3; ++r) {
        const int ir = min(max(i + r - 1, 0), HH - 1);
        const float* rowp = x + ((size_t)b * HH + ir) * WW * CC;
#pragma unroll
        for (int s = 0; s < 4; ++s) {
            int u = t + s * 256;
            int slot = u >> 4, c4 = u & 15;
            int jj = min(max(j0 + slot - 1, 0), WW - 1);
            float4 v = *(const float4*)(rowp + (size_t)jj * CC + c4 * 4);
            uint2 pk;
            pk.x = f2bfbits(v.x) | (f2bfbits(v.y) << 16);
            pk.y = f2bfbits(v.z) | (f2bfbits(v.w) << 16);
            *(uint2*)(&xrow[r][slot][c4 * 4]) = pk;
        }
        if (t < 32) {
            int u = t + 1024;
            int slot = u >> 4, c4 = u & 15;
            int jj = min(max(j0 + slot - 1, 0), WW - 1);
            float4 v = *(const float4*)(rowp + (size_t)jj * CC + c4 * 4);
            uint2 pk;
            pk.x = f2bfbits(v.x) | (f2bfbits(v.y) << 16);
            pk.y = f2bfbits(v.z) | (f2bfbits(v.w) << 16);
            *(uint2*)(&xrow[r][slot][c4 * 4]) = pk;
        }
    }
    // ---- phase 0b: DENSE stage w1b/w2bT -> padded LDS (16B/thread/instr) ----
#pragma unroll
    for (int s = 0; s < 2; ++s) {
        int u = t + s * 256;                   // u < 512: row = u>>3, seg = u&7
        int row = u >> 3, seg = u & 7;
        uint4 v = *(const uint4*)(w1b + row * CC + seg * 8);
        *(uint4*)(&w1L[row][seg * 8]) = v;
    }
    if (t < 128) {
        int row = t >> 3, seg = t & 7;
        uint4 v = *(const uint4*)(w2bT + row * CC + seg * 8);
        *(uint4*)(&w2L[row][seg * 8]) = v;
    }
    __syncthreads();   // the ONLY barrier

    // ---- GEMM1: wave w owns px [w*16,w*16+16); A + B from LDS (r6 recipe) ----
    {
        short8v af[2];
#pragma unroll
        for (int ks = 0; ks < 2; ++ks)
            af[ks] = *(const short8v*)(&xrow[1][w * 16 + lr + 1][ks * 32 + lq * 8]);

        f32x4 acc[4];
#pragma unroll
        for (int n = 0; n < 4; ++n) acc[n] = (f32x4){0.f, 0.f, 0.f, 0.f};
#pragma unroll
        for (int ks = 0; ks < 2; ++ks)
#pragma unroll
            for (int n = 0; n < 4; ++n) {
                short8v bf = *(const short8v*)(&w1L[n * 16 + lr][ks * 32 + lq * 8]);
                acc[n] = __builtin_amdgcn_mfma_f32_16x16x32_bf16(af[ks], bf, acc[n], 0, 0, 0);
            }
#pragma unroll
        for (int n = 0; n < 4; ++n) {
            const int d = n * 16 + lr;
            const float s = scalef[d], bb = biasf[d];
#pragma unroll
            for (int r = 0; r < 4; ++r) {
                float hv = fmaxf(fmaf(acc[n][r], s, bb), 0.f);
                hL[w][lq * 4 + r][d] = (ushort_t)f2bfbits(hv);
            }
        }
    }
    // same-wave LDS handoff (compiler lgkmcnt)

    // ---- GEMM2: kern = h @ w2 + b2 via MFMA (M=16, N=16 pad, K=64; r9 recipe) ----
    {
        f32x4 acc2 = (f32x4){0.f, 0.f, 0.f, 0.f};
#pragma unroll
        for (int ks = 0; ks < 2; ++ks) {
            short8v a2  = *(const short8v*)(&hL[w][lr][ks * 32 + lq * 8]);
            short8v b2v = *(const short8v*)(&w2L[lr][ks * 32 + lq * 8]);
            acc2 = __builtin_amdgcn_mfma_f32_16x16x32_bf16(a2, b2v, acc2, 0, 0, 0);
        }
        if (lr < KK) {
            const float bk = b2f[lr];
#pragma unroll
            for (int r = 0; r < 4; ++r)
                kS[w * 16 + lq * 4 + r][lr] = acc2[r] + bk;
        }
    }
    // same-wave handoff; dense kout drain: 36 contiguous float4 per wave
    {
        float* kbase = kout + (size_t)(p0 + w * 16) * KK;
        if (l < 36) {
            float v[4];
#pragma unroll
            for (int e = 0; e < 4; ++e) {
                int f = l * 4 + e;
                v[e] = kS[w * 16 + f / KK][f % KK];
            }
            *(f32x4*)(kbase + l * 4) = (f32x4){v[0], v[1], v[2], v[3]};
        }
    }

    // ---- involution, WAVE-LOCAL dense mapping: wave w drains its own 16-px block ----
    // flat = r*64 + l over wave's 16px * 64ch region; pix = w*16 + (flat>>4) stays in
    // wave w's kS rows (race-free, same-wave handoff valid). Store instr = 1KB dense.
    {
        float* obase = out + (size_t)(p0 + w * 16) * CC;
#pragma unroll
        for (int r = 0; r < 4; ++r) {
            const int flat = r * 64 + l;
            const int pxo = flat >> 4;           // 0..15 within wave's block
            const int g = flat & 15;             // 4-ch granule
            const int pix = w * 16 + pxo;        // block-local pixel
            float a0 = 0.f, a1 = 0.f, a2 = 0.f, a3 = 0.f;
#pragma unroll
            for (int ti = 0; ti < 3; ++ti) {
                const int ii = i + ti - 1;
                if (ii < 0 || ii >= HH) continue;      // block-uniform skip
#pragma unroll
                for (int tj = 0; tj < 3; ++tj) {
                    int jj = j0 + pix + tj - 1;
                    bool valid = (jj >= 0) && (jj < WW);
                    float kv = valid ? kS[pix][ti * 3 + tj] : 0.f;
                    uint2 u = *(const uint2*)(&xrow[ti][pix + tj][g * 4]);
                    a0 = fmaf(kv, bflo(u.x), a0);
                    a1 = fmaf(kv, bfhi(u.x), a1);
                    a2 = fmaf(kv, bflo(u.y), a2);
                    a3 = fmaf(kv, bfhi(u.y), a3);
                }
            }
            *(f32x4*)(obase + (size_t)flat * 4) = (f32x4){a0, a1, a2, a3};
        }
    }
}

extern "C" void kernel_launch(void* const* d_in, const int* in_sizes, int n_in,
                              void* d_out, int out_size, void* d_ws, size_t ws_size,
                              hipStream_t stream) {
    const float* x       = (const float*)d_in[0];
    const float* w1      = (const float*)d_in[1];
    const float* b1      = (const float*)d_in[2];
    const float* gamma   = (const float*)d_in[3];
    const float* beta    = (const float*)d_in[4];
    const float* bn_mean = (const float*)d_in[5];
    const float* bn_var  = (const float*)d_in[6];
    const float* w2      = (const float*)d_in[7];
    const float* b2      = (const float*)d_in[8];

    ushort_t* w1b  = (ushort_t*)d_ws;                // 4096 ush = 8192 B
    ushort_t* w2bT = w1b + CC * CC;                  // 1024 ush = 2048 B
    float* scalef  = (float*)(w2bT + 16 * CC);       // 64
    float* biasf   = scalef + CC;                    // 64
    float* b2f     = biasf + CC;                     // 9

    float* out  = (float*)d_out;
    float* kout = out + (size_t)NPIX * CC;

    hipLaunchKernelGGL(setup_kernel, dim3(20), dim3(256), 0, stream,
                       w1, b1, gamma, beta, bn_mean, bn_var, w2, b2,
                       w1b, w2bT, scalef, biasf, b2f);

    hipLaunchKernelGGL(invol_fused, dim3(NPIX / 64), dim3(256), 0, stream,
                       x, w1b, w2bT, scalef, biasf, b2f, out, kout);
}

// Round 20
// 28.862 us; speedup vs baseline: 1.7273x; 1.1063x over previous
//
#include <hip/hip_runtime.h>

typedef unsigned int uint;
typedef unsigned short ushort_t;
typedef __attribute__((ext_vector_type(8))) short short8v;   // 8 bf16 (4 VGPRs)
typedef __attribute__((ext_vector_type(4))) float f32x4;

#define BATCH 8
#define HH 128
#define WW 128
#define CC 64
#define NPIX (BATCH * HH * WW)   // 131072
#define KK 9
#define BN_EPS 1e-3f
#define ROWS 4                    // output rows per block
#define NBLK (NPIX / (64 * ROWS)) // 512 = 2 blocks/CU, co-resident

__device__ __forceinline__ uint f2bfbits(float f) {
    uint u = __float_as_uint(f);
    return (u + 0x7fffu + ((u >> 16) & 1u)) >> 16;   // RNE
}
__device__ __forceinline__ float bflo(uint u) { return __uint_as_float(u << 16); }
__device__ __forceinline__ float bfhi(uint u) { return __uint_as_float(u & 0xffff0000u); }

// ---- setup: w1 -> bf16 [d][c]; w2 -> bf16 transposed [k][d]; fold BN ----
__global__ void setup_kernel(const float* __restrict__ w1,
                             const float* __restrict__ b1,
                             const float* __restrict__ gamma,
                             const float* __restrict__ beta,
                             const float* __restrict__ bn_mean,
                             const float* __restrict__ bn_var,
                             const float* __restrict__ w2,
                             const float* __restrict__ b2,
                             ushort_t* __restrict__ w1b,    // [64][64] bf16: w1b[d][c] = w1[c][d]
                             ushort_t* __restrict__ w2bT,   // [16][64] bf16: w2bT[k][d] = w2[d][k]
                             float* __restrict__ scalef,    // [64]
                             float* __restrict__ biasf,     // [64]
                             float* __restrict__ b2f)       // [9]
{
    int t = blockIdx.x * blockDim.x + threadIdx.x;
    int nt = gridDim.x * blockDim.x;
    for (int idx = t; idx < CC * CC; idx += nt) {
        int d = idx >> 6, c = idx & 63;
        w1b[idx] = (ushort_t)f2bfbits(w1[c * CC + d]);
    }
    for (int idx = t; idx < 16 * CC; idx += nt) {
        int k = idx >> 6, d = idx & 63;
        w2bT[idx] = (k < KK) ? (ushort_t)f2bfbits(w2[d * KK + k]) : (ushort_t)0;
    }
    if (t < CC) {
        float s = gamma[t] * rsqrtf(bn_var[t] + BN_EPS);
        scalef[t] = s;
        biasf[t] = (b1[t] - bn_mean[t]) * s + beta[t];
    }
    if (t < KK) b2f[t] = b2[t];
}

// ---- fused rolling-row kernel: ring-4 LDS rows, 4 output rows per block ----
__global__ __launch_bounds__(256) void invol_fused(
    const float* __restrict__ x,
    const ushort_t* __restrict__ w1b,
    const ushort_t* __restrict__ w2bT,
    const float* __restrict__ scalef,
    const float* __restrict__ biasf,
    const float* __restrict__ b2f,
    float* __restrict__ out,     // [NPIX][64]
    float* __restrict__ kout)    // [NPIX][9]
{
    __shared__ ushort_t xrow[4][66][72];   // ring of 4 staged rows (bf16), 38016 B
    __shared__ ushort_t w1L[64][72];       // w1 tile, 9216 B
    __shared__ ushort_t w2L[16][72];       // w2^T tile, 2304 B
    __shared__ ushort_t hL[4][16][72];     // per-wave h, 9216 B (wave-private)
    __shared__ float    kS[64][12];        // kern per pixel, 3072 B (wave-private rows)

    const int t = threadIdx.x;
    const int w = __builtin_amdgcn_readfirstlane(t >> 6);
    const int l = t & 63;
    const int lq = l >> 4, lr = l & 15;
    int bid = blockIdx.x;
    bid = (bid & 7) * (NBLK / 8) + (bid >> 3);   // XCD swizzle (512 = 8*64, bijective)

    const int jhalf = bid & 1;
    const int grp = (bid >> 1) & 31;
    const int b = bid >> 6;
    const int i0 = grp * ROWS;
    const int j0 = jhalf * 64;

    // ---- helpers ----
    auto stage_row_to_regs = [&](int ro, float4* sv) {
        const float* rowp = x + ((size_t)b * HH + min(max(ro, 0), HH - 1)) * WW * CC;
#pragma unroll
        for (int s = 0; s < 4; ++s) {
            int u = t + s * 256;
            int slot = u >> 4, c4 = u & 15;
            int jj = min(max(j0 + slot - 1, 0), WW - 1);
            sv[s] = *(const float4*)(rowp + (size_t)jj * CC + c4 * 4);
        }
        if (t < 32) {
            int u = t + 1024;
            int slot = u >> 4, c4 = u & 15;
            int jj = min(max(j0 + slot - 1, 0), WW - 1);
            sv[4] = *(const float4*)(rowp + (size_t)jj * CC + c4 * 4);
        }
    };
    auto write_row_to_lds = [&](int ringslot, const float4* sv) {
#pragma unroll
        for (int s = 0; s < 4; ++s) {
            int u = t + s * 256;
            int slot = u >> 4, c4 = u & 15;
            uint2 pk;
            pk.x = f2bfbits(sv[s].x) | (f2bfbits(sv[s].y) << 16);
            pk.y = f2bfbits(sv[s].z) | (f2bfbits(sv[s].w) << 16);
            *(uint2*)(&xrow[ringslot][slot][c4 * 4]) = pk;
        }
        if (t < 32) {
            int u = t + 1024;
            int slot = u >> 4, c4 = u & 15;
            uint2 pk;
            pk.x = f2bfbits(sv[4].x) | (f2bfbits(sv[4].y) << 16);
            pk.y = f2bfbits(sv[4].z) | (f2bfbits(sv[4].w) << 16);
            *(uint2*)(&xrow[ringslot][slot][c4 * 4]) = pk;
        }
    };

    // ---- init: stage rows i0-1, i0, i0+1 -> slots 0,1,2; weights -> LDS ----
    {
        float4 sv[5];
#pragma unroll
        for (int r = 0; r < 3; ++r) {
            stage_row_to_regs(i0 - 1 + r, sv);
            write_row_to_lds(r, sv);
        }
    }
#pragma unroll
    for (int s = 0; s < 2; ++s) {
        int u = t + s * 256;
        int row = u >> 3, seg = u & 7;
        uint4 v = *(const uint4*)(w1b + row * CC + seg * 8);
        *(uint4*)(&w1L[row][seg * 8]) = v;
    }
    if (t < 128) {
        int row = t >> 3, seg = t & 7;
        uint4 v = *(const uint4*)(w2bT + row * CC + seg * 8);
        *(uint4*)(&w2L[row][seg * 8]) = v;
    }
    __syncthreads();

    // ---- row loop (fully unrolled: ring indices compile-time) ----
#pragma unroll
    for (int r = 0; r < ROWS; ++r) {
        const int i = i0 + r;
        const int p0 = ((b * HH + i) * WW) + j0;      // global pixel base of this row-half
        const int sTop = r & 3, sMid = (r + 1) & 3, sBot = (r + 2) & 3, sNew = (r + 3) & 3;

        // T14: issue next row's global loads now (land after compute)
        float4 sv[5];
        if (r < ROWS - 1) stage_row_to_regs(i0 + r + 2, sv);

        // ---- GEMM1: wave w owns px [w*16,w*16+16); A from mid slot (r6 recipe) ----
        {
            short8v af[2];
#pragma unroll
            for (int ks = 0; ks < 2; ++ks)
                af[ks] = *(const short8v*)(&xrow[sMid][w * 16 + lr + 1][ks * 32 + lq * 8]);

            f32x4 acc[4];
#pragma unroll
            for (int n = 0; n < 4; ++n) acc[n] = (f32x4){0.f, 0.f, 0.f, 0.f};
#pragma unroll
            for (int ks = 0; ks < 2; ++ks)
#pragma unroll
                for (int n = 0; n < 4; ++n) {
                    short8v bf = *(const short8v*)(&w1L[n * 16 + lr][ks * 32 + lq * 8]);
                    acc[n] = __builtin_amdgcn_mfma_f32_16x16x32_bf16(af[ks], bf, acc[n], 0, 0, 0);
                }
#pragma unroll
            for (int n = 0; n < 4; ++n) {
                const int d = n * 16 + lr;
                const float s = scalef[d], bb = biasf[d];
#pragma unroll
                for (int q = 0; q < 4; ++q) {
                    float hv = fmaxf(fmaf(acc[n][q], s, bb), 0.f);
                    hL[w][lq * 4 + q][d] = (ushort_t)f2bfbits(hv);
                }
            }
        }
        // same-wave LDS handoff (compiler lgkmcnt)

        // ---- GEMM2: kern = h @ w2 + b2 (M=16, N=16 pad, K=64; r9 recipe) ----
        {
            f32x4 acc2 = (f32x4){0.f, 0.f, 0.f, 0.f};
#pragma unroll
            for (int ks = 0; ks < 2; ++ks) {
                short8v a2  = *(const short8v*)(&hL[w][lr][ks * 32 + lq * 8]);
                short8v b2v = *(const short8v*)(&w2L[lr][ks * 32 + lq * 8]);
                acc2 = __builtin_amdgcn_mfma_f32_16x16x32_bf16(a2, b2v, acc2, 0, 0, 0);
            }
            if (lr < KK) {
                const float bk = b2f[lr];
#pragma unroll
                for (int q = 0; q < 4; ++q)
                    kS[w * 16 + lq * 4 + q][lr] = acc2[q] + bk;
            }
        }
        // same-wave handoff; dense kout drain: 36 contiguous float4 per wave
        {
            float* kbase = kout + (size_t)(p0 + w * 16) * KK;
            if (l < 36) {
                float v[4];
#pragma unroll
                for (int e = 0; e < 4; ++e) {
                    int f = l * 4 + e;
                    v[e] = kS[w * 16 + f / KK][f % KK];
                }
                *(f32x4*)(kbase + l * 4) = (f32x4){v[0], v[1], v[2], v[3]};
            }
        }

        // ---- involution, wave-local dense (r19 recipe); rows from ring slots ----
        {
            float* obase = out + (size_t)(p0 + w * 16) * CC;
#pragma unroll
            for (int rr = 0; rr < 4; ++rr) {
                const int flat = rr * 64 + l;
                const int pxo = flat >> 4;
                const int g = flat & 15;
                const int pix = w * 16 + pxo;
                float a0 = 0.f, a1 = 0.f, a2 = 0.f, a3 = 0.f;
#pragma unroll
                for (int ti = 0; ti < 3; ++ti) {
                    const int ii = i + ti - 1;
                    if (ii < 0 || ii >= HH) continue;      // block-uniform skip
                    const int sl = (ti == 0) ? sTop : (ti == 1) ? sMid : sBot;
#pragma unroll
                    for (int tj = 0; tj < 3; ++tj) {
                        int jj = j0 + pix + tj - 1;
                        bool valid = (jj >= 0) && (jj < WW);
                        float kv = valid ? kS[pix][ti * 3 + tj] : 0.f;
                        uint2 u = *(const uint2*)(&xrow[sl][pix + tj][g * 4]);
                        a0 = fmaf(kv, bflo(u.x), a0);
                        a1 = fmaf(kv, bfhi(u.x), a1);
                        a2 = fmaf(kv, bflo(u.y), a2);
                        a3 = fmaf(kv, bfhi(u.y), a3);
                    }
                }
                *(f32x4*)(obase + (size_t)flat * 4) = (f32x4){a0, a1, a2, a3};
            }
        }

        // ---- land next row into dead ring slot; barrier bounds cross-wave halo ----
        if (r < ROWS - 1) {
            write_row_to_lds(sNew, sv);
            __syncthreads();
        }
    }
}

extern "C" void kernel_launch(void* const* d_in, const int* in_sizes, int n_in,
                              void* d_out, int out_size, void* d_ws, size_t ws_size,
                              hipStream_t stream) {
    const float* x       = (const float*)d_in[0];
    const float* w1      = (const float*)d_in[1];
    const float* b1      = (const float*)d_in[2];
    const float* gamma   = (const float*)d_in[3];
    const float* beta    = (const float*)d_in[4];
    const float* bn_mean = (const float*)d_in[5];
    const float* bn_var  = (const float*)d_in[6];
    const float* w2      = (const float*)d_in[7];
    const float* b2      = (const float*)d_in[8];

    ushort_t* w1b  = (ushort_t*)d_ws;                // 4096 ush = 8192 B
    ushort_t* w2bT = w1b + CC * CC;                  // 1024 ush = 2048 B
    float* scalef  = (float*)(w2bT + 16 * CC);       // 64
    float* biasf   = scalef + CC;                    // 64
    float* b2f     = biasf + CC;                     // 9

    float* out  = (float*)d_out;
    float* kout = out + (size_t)NPIX * CC;

    hipLaunchKernelGGL(setup_kernel, dim3(20), dim3(256), 0, stream,
                       w1, b1, gamma, beta, bn_mean, bn_var, w2, b2,
                       w1b, w2bT, scalef, biasf, b2f);

    hipLaunchKernelGGL(invol_fused, dim3(NBLK), dim3(256), 0, stream,
                       x, w1b, w2bT, scalef, biasf, b2f, out, kout);
}

// Round 21
// 28.788 us; speedup vs baseline: 1.7317x; 1.0026x over previous
//
#include <hip/hip_runtime.h>

typedef unsigned int uint;
typedef unsigned short ushort_t;
typedef __attribute__((ext_vector_type(8))) short short8v;   // 8 bf16 (4 VGPRs)
typedef __attribute__((ext_vector_type(4))) float f32x4;

#define BATCH 8
#define HH 128
#define WW 128
#define CC 64
#define NPIX (BATCH * HH * WW)   // 131072
#define KK 9
#define BN_EPS 1e-3f
#define ROWS 4                    // output rows per block
#define NBLK (NPIX / (64 * ROWS)) // 512 = 2 blocks/CU, co-resident

__device__ __forceinline__ uint f2bfbits(float f) {
    uint u = __float_as_uint(f);
    return (u + 0x7fffu + ((u >> 16) & 1u)) >> 16;   // RNE
}
__device__ __forceinline__ float bflo(uint u) { return __uint_as_float(u << 16); }
__device__ __forceinline__ float bfhi(uint u) { return __uint_as_float(u & 0xffff0000u); }

// ---- setup: w1 -> bf16 [d][c]; w2 -> bf16 transposed [k][d]; fold BN ----
__global__ void setup_kernel(const float* __restrict__ w1,
                             const float* __restrict__ b1,
                             const float* __restrict__ gamma,
                             const float* __restrict__ beta,
                             const float* __restrict__ bn_mean,
                             const float* __restrict__ bn_var,
                             const float* __restrict__ w2,
                             const float* __restrict__ b2,
                             ushort_t* __restrict__ w1b,    // [64][64] bf16: w1b[d][c] = w1[c][d]
                             ushort_t* __restrict__ w2bT,   // [16][64] bf16: w2bT[k][d] = w2[d][k]
                             float* __restrict__ scalef,    // [64]
                             float* __restrict__ biasf,     // [64]
                             float* __restrict__ b2f)       // [9]
{
    int t = blockIdx.x * blockDim.x + threadIdx.x;
    int nt = gridDim.x * blockDim.x;
    for (int idx = t; idx < CC * CC; idx += nt) {
        int d = idx >> 6, c = idx & 63;
        w1b[idx] = (ushort_t)f2bfbits(w1[c * CC + d]);
    }
    for (int idx = t; idx < 16 * CC; idx += nt) {
        int k = idx >> 6, d = idx & 63;
        w2bT[idx] = (k < KK) ? (ushort_t)f2bfbits(w2[d * KK + k]) : (ushort_t)0;
    }
    if (t < CC) {
        float s = gamma[t] * rsqrtf(bn_var[t] + BN_EPS);
        scalef[t] = s;
        biasf[t] = (b1[t] - bn_mean[t]) * s + beta[t];
    }
    if (t < KK) b2f[t] = b2[t];
}

// ---- fused rolling-row kernel, GEMM pipelined one row ahead of involution ----
__global__ __launch_bounds__(256) void invol_fused(
    const float* __restrict__ x,
    const ushort_t* __restrict__ w1b,
    const ushort_t* __restrict__ w2bT,
    const float* __restrict__ scalef,
    const float* __restrict__ biasf,
    const float* __restrict__ b2f,
    float* __restrict__ out,     // [NPIX][64]
    float* __restrict__ kout)    // [NPIX][9]
{
    __shared__ ushort_t xrow[4][66][72];   // ring of 4 staged rows (bf16), 38016 B
    __shared__ ushort_t w1L[64][72];       // w1 tile, 9216 B
    __shared__ ushort_t w2L[16][72];       // w2^T tile, 2304 B
    __shared__ ushort_t hL[4][16][72];     // per-wave h, 9216 B (wave-private, per-epoch)
    __shared__ float    kS[2][64][12];     // kern double-buffer, 6144 B (wave-private rows)

    const int t = threadIdx.x;
    const int w = __builtin_amdgcn_readfirstlane(t >> 6);
    const int l = t & 63;
    const int lq = l >> 4, lr = l & 15;
    int bid = blockIdx.x;
    bid = (bid & 7) * (NBLK / 8) + (bid >> 3);   // XCD swizzle (512 = 8*64, bijective)

    const int jhalf = bid & 1;
    const int grp = (bid >> 1) & 31;
    const int b = bid >> 6;
    const int i0 = grp * ROWS;
    const int j0 = jhalf * 64;

    // slot(row) = (row - i0 + 1) & 3
    auto stage_row_to_regs = [&](int ro, float4* sv) {
        const float* rowp = x + ((size_t)b * HH + min(max(ro, 0), HH - 1)) * WW * CC;
#pragma unroll
        for (int s = 0; s < 4; ++s) {
            int u = t + s * 256;
            int slot = u >> 4, c4 = u & 15;
            int jj = min(max(j0 + slot - 1, 0), WW - 1);
            sv[s] = *(const float4*)(rowp + (size_t)jj * CC + c4 * 4);
        }
        if (t < 32) {
            int u = t + 1024;
            int slot = u >> 4, c4 = u & 15;
            int jj = min(max(j0 + slot - 1, 0), WW - 1);
            sv[4] = *(const float4*)(rowp + (size_t)jj * CC + c4 * 4);
        }
    };
    auto write_row_to_lds = [&](int ringslot, const float4* sv) {
#pragma unroll
        for (int s = 0; s < 4; ++s) {
            int u = t + s * 256;
            int slot = u >> 4, c4 = u & 15;
            uint2 pk;
            pk.x = f2bfbits(sv[s].x) | (f2bfbits(sv[s].y) << 16);
            pk.y = f2bfbits(sv[s].z) | (f2bfbits(sv[s].w) << 16);
            *(uint2*)(&xrow[ringslot][slot][c4 * 4]) = pk;
        }
        if (t < 32) {
            int u = t + 1024;
            int slot = u >> 4, c4 = u & 15;
            uint2 pk;
            pk.x = f2bfbits(sv[4].x) | (f2bfbits(sv[4].y) << 16);
            pk.y = f2bfbits(sv[4].z) | (f2bfbits(sv[4].w) << 16);
            *(uint2*)(&xrow[ringslot][slot][c4 * 4]) = pk;
        }
    };

    // GEMM chain for one row: A from xrow[sMid], h->hL, kern->kS[kbuf] + kout drain
    auto gemm_chain = [&](int sMid, int kbuf, int p0row) {
        // GEMM1 (r6 recipe)
        short8v af[2];
#pragma unroll
        for (int ks = 0; ks < 2; ++ks)
            af[ks] = *(const short8v*)(&xrow[sMid][w * 16 + lr + 1][ks * 32 + lq * 8]);
        f32x4 acc[4];
#pragma unroll
        for (int n = 0; n < 4; ++n) acc[n] = (f32x4){0.f, 0.f, 0.f, 0.f};
#pragma unroll
        for (int ks = 0; ks < 2; ++ks)
#pragma unroll
            for (int n = 0; n < 4; ++n) {
                short8v bf = *(const short8v*)(&w1L[n * 16 + lr][ks * 32 + lq * 8]);
                acc[n] = __builtin_amdgcn_mfma_f32_16x16x32_bf16(af[ks], bf, acc[n], 0, 0, 0);
            }
#pragma unroll
        for (int n = 0; n < 4; ++n) {
            const int d = n * 16 + lr;
            const float s = scalef[d], bb = biasf[d];
#pragma unroll
            for (int q = 0; q < 4; ++q) {
                float hv = fmaxf(fmaf(acc[n][q], s, bb), 0.f);
                hL[w][lq * 4 + q][d] = (ushort_t)f2bfbits(hv);
            }
        }
        // same-wave handoff (lgkmcnt); GEMM2 (r9 recipe)
        f32x4 acc2 = (f32x4){0.f, 0.f, 0.f, 0.f};
#pragma unroll
        for (int ks = 0; ks < 2; ++ks) {
            short8v a2  = *(const short8v*)(&hL[w][lr][ks * 32 + lq * 8]);
            short8v b2v = *(const short8v*)(&w2L[lr][ks * 32 + lq * 8]);
            acc2 = __builtin_amdgcn_mfma_f32_16x16x32_bf16(a2, b2v, acc2, 0, 0, 0);
        }
        if (lr < KK) {
            const float bk = b2f[lr];
#pragma unroll
            for (int q = 0; q < 4; ++q)
                kS[kbuf][w * 16 + lq * 4 + q][lr] = acc2[q] + bk;
        }
        // same-wave handoff; dense kout drain (36 contiguous float4 per wave)
        float* kbase = kout + (size_t)(p0row + w * 16) * KK;
        if (l < 36) {
            float v[4];
#pragma unroll
            for (int e = 0; e < 4; ++e) {
                int f = l * 4 + e;
                v[e] = kS[kbuf][w * 16 + f / KK][f % KK];
            }
            *(f32x4*)(kbase + l * 4) = (f32x4){v[0], v[1], v[2], v[3]};
        }
    };

    // ---- init: stage rows i0-1..i0+1 -> slots 0,1,2; weights -> LDS; barrier ----
    {
        float4 sv[5];
#pragma unroll
        for (int r = 0; r < 3; ++r) {
            stage_row_to_regs(i0 - 1 + r, sv);
            write_row_to_lds(r, sv);
        }
    }
#pragma unroll
    for (int s = 0; s < 2; ++s) {
        int u = t + s * 256;
        int row = u >> 3, seg = u & 7;
        uint4 v = *(const uint4*)(w1b + row * CC + seg * 8);
        *(uint4*)(&w1L[row][seg * 8]) = v;
    }
    if (t < 128) {
        int row = t >> 3, seg = t & 7;
        uint4 v = *(const uint4*)(w2bT + row * CC + seg * 8);
        *(uint4*)(&w2L[row][seg * 8]) = v;
    }
    __syncthreads();

    // ---- prologue: GEMM for row i0 into kS[0] (reads slot 1, init-staged) ----
    gemm_chain(1, 0, (b * HH + i0) * WW + j0);

    // ---- epochs: GEMM(r+1) || invol(r), land row r+2, barrier ----
#pragma unroll
    for (int r = 0; r < ROWS; ++r) {
        const int i = i0 + r;
        const int p0 = (b * HH + i) * WW + j0;
        const int cur = r & 1, alt = cur ^ 1;
        const int sTop = r & 3, sMid = (r + 1) & 3, sBot = (r + 2) & 3, sNew = (r + 3) & 3;

        // T14: issue stage loads for row i0+r+2 (lands as slot sNew at epoch end)
        float4 sv[5];
        if (r < ROWS - 1) stage_row_to_regs(i0 + r + 2, sv);

        // GEMM chain for NEXT row (i0+r+1) into kS[alt]; reads sBot (= sMid(r+1))
        if (r < ROWS - 1)
            gemm_chain(sBot, alt, (b * HH + (i + 1)) * WW + j0);

        // involution for CURRENT row from kS[cur] (produced last epoch / prologue)
        {
            float* obase = out + (size_t)(p0 + w * 16) * CC;
#pragma unroll
            for (int rr = 0; rr < 4; ++rr) {
                const int flat = rr * 64 + l;
                const int pxo = flat >> 4;
                const int g = flat & 15;
                const int pix = w * 16 + pxo;
                // vectorized kern load: 3 x b128
                f32x4 k0 = *(const f32x4*)(&kS[cur][pix][0]);
                f32x4 k1 = *(const f32x4*)(&kS[cur][pix][4]);
                f32x4 k2 = *(const f32x4*)(&kS[cur][pix][8]);
                float kern[KK] = {k0[0], k0[1], k0[2], k0[3], k1[0], k1[1], k1[2], k1[3], k2[0]};
                float a0 = 0.f, a1 = 0.f, a2 = 0.f, a3 = 0.f;
#pragma unroll
                for (int ti = 0; ti < 3; ++ti) {
                    const int ii = i + ti - 1;
                    if (ii < 0 || ii >= HH) continue;      // block-uniform skip
                    const int sl = (ti == 0) ? sTop : (ti == 1) ? sMid : sBot;
#pragma unroll
                    for (int tj = 0; tj < 3; ++tj) {
                        int jj = j0 + pix + tj - 1;
                        bool valid = (jj >= 0) && (jj < WW);
                        float kv = valid ? kern[ti * 3 + tj] : 0.f;
                        uint2 u = *(const uint2*)(&xrow[sl][pix + tj][g * 4]);
                        a0 = fmaf(kv, bflo(u.x), a0);
                        a1 = fmaf(kv, bfhi(u.x), a1);
                        a2 = fmaf(kv, bflo(u.y), a2);
                        a3 = fmaf(kv, bfhi(u.y), a3);
                    }
                }
                *(f32x4*)(obase + (size_t)flat * 4) = (f32x4){a0, a1, a2, a3};
            }
        }

        // land next row into dead ring slot; barrier bounds cross-wave halo reads
        if (r < ROWS - 1) {
            write_row_to_lds(sNew, sv);
            __syncthreads();
        }
    }
}

extern "C" void kernel_launch(void* const* d_in, const int* in_sizes, int n_in,
                              void* d_out, int out_size, void* d_ws, size_t ws_size,
                              hipStream_t stream) {
    const float* x       = (const float*)d_in[0];
    const float* w1      = (const float*)d_in[1];
    const float* b1      = (const float*)d_in[2];
    const float* gamma   = (const float*)d_in[3];
    const float* beta    = (const float*)d_in[4];
    const float* bn_mean = (const float*)d_in[5];
    const float* bn_var  = (const float*)d_in[6];
    const float* w2      = (const float*)d_in[7];
    const float* b2      = (const float*)d_in[8];

    ushort_t* w1b  = (ushort_t*)d_ws;                // 4096 ush = 8192 B
    ushort_t* w2bT = w1b + CC * CC;                  // 1024 ush = 2048 B
    float* scalef  = (float*)(w2bT + 16 * CC);       // 64
    float* biasf   = scalef + CC;                    // 64
    float* b2f     = biasf + CC;                     // 9

    float* out  = (float*)d_out;
    float* kout = out + (size_t)NPIX * CC;

    hipLaunchKernelGGL(setup_kernel, dim3(20), dim3(256), 0, stream,
                       w1, b1, gamma, beta, bn_mean, bn_var, w2, b2,
                       w1b, w2bT, scalef, biasf, b2f);

    hipLaunchKernelGGL(invol_fused, dim3(NBLK), dim3(256), 0, stream,
                       x, w1b, w2bT, scalef, biasf, b2f, out, kout);
}